// Round 8
// baseline (488.532 us; speedup 1.0000x reference)
//
#include <hip/hip_runtime.h>
#include <hip/hip_cooperative_groups.h>
#include <hip/hip_bf16.h>
#include <math.h>

namespace cg = cooperative_groups;

#define B_ 1024
#define S_ 512
#define E_ 1024
#define D_ 2048
#define SMOOTH 10.0f

typedef __attribute__((ext_vector_type(8))) short bf16x8;
typedef __attribute__((ext_vector_type(4))) float f32x4;

__device__ __forceinline__ short f2bf(float f) {
    __hip_bfloat16 h = __float2bfloat16(f);
    short s; __builtin_memcpy(&s, &h, 2); return s;
}
__device__ __forceinline__ float bf2f(short s) {
    __hip_bfloat16 h; __builtin_memcpy(&h, &s, 2);
    return __bfloat162float(h);
}

__device__ __forceinline__ void gload16(const short* g, short* l) {
    __builtin_amdgcn_global_load_lds(
        (const __attribute__((address_space(1))) void*)(g),
        (__attribute__((address_space(3))) void*)(l), 16, 0, 0);
}

__inline__ __device__ float waveReduceMax(float v) {
#pragma unroll
    for (int o = 32; o; o >>= 1) v = fmaxf(v, __shfl_xor(v, o));
    return v;
}
__inline__ __device__ float waveReduceSum(float v) {
#pragma unroll
    for (int o = 32; o; o >>= 1) v += __shfl_xor(v, o);
    return v;
}

// ---------------- transpose helper (32x32 tile via LDS) ----------------
__device__ __forceinline__ void transpose_split(const float* __restrict__ in,
                                                short* __restrict__ out,
                                                int C, int r0, int c0,
                                                int ldo, int loOff,
                                                int tid, float (*t)[33]) {
    int cx = tid & 31, ry0 = tid >> 5;
#pragma unroll
    for (int i = 0; i < 4; i++) {
        int ry = ry0 + i * 8;
        t[ry][cx] = in[(size_t)(r0 + ry) * C + c0 + cx];
    }
    __syncthreads();
    int rx = tid & 31, cy0 = tid >> 5;
#pragma unroll
    for (int i = 0; i < 4; i++) {
        int cy = cy0 + i * 8;
        float v = t[rx][cy];
        size_t o = (size_t)(c0 + cy) * ldo + r0 + rx;
        short h = f2bf(v);
        out[o] = h;
        if (loOff > 0) out[o + loOff] = f2bf(v - bf2f(h));
    }
}

// ---------------- prep task body (shared by mega + fallback) ----------------
struct KArgs {
    const float *cf, *emb, *fc1w, *fc2w, *bn1g, *bn1b, *bn2g, *bn2b, *fc3w;
    short *A1, *A2, *Bt1, *Bt2, *cfT, *Ws, *Wv3, *A4;
    float *invn, *Z1, *Z2, *part1, *part2, *P1, *P2, *P3, *P4;
    float *weights_v, *emb_concept;
};

__device__ __forceinline__ void prep_task(const KArgs& a, int task, int tid,
                                          float (*t)[33], float* red) {
    if (task < 512) {
        int row = task;
        const float* x = a.cf + (size_t)row * D_;
        short* aa = a.A1 + (size_t)row * (2 * D_);
        float ss = 0.f;
#pragma unroll
        for (int j = 0; j < 8; j++) {
            int i = j * 256 + tid;
            float v = x[i];
            short h = f2bf(v);
            aa[i] = h;
            aa[D_ + i] = f2bf(v - bf2f(h));
            ss += v * v;
        }
        ss = waveReduceSum(ss);
        if ((tid & 63) == 0) red[tid >> 6] = ss;
        __syncthreads();
        if (tid == 0) {
            float s = red[0] + red[1] + red[2] + red[3];
            a.invn[row] = 1.0f / (sqrtf(s) + 1e-8f);
        }
    } else if (task < 1024) {
        int r0 = (task - 512) * 2;
#pragma unroll
        for (int rr = 0; rr < 2; rr++) {
            int row = r0 + rr;
            const float* x = a.emb + (size_t)row * E_;
            short* aa = a.A2 + (size_t)row * (2 * E_);
#pragma unroll
            for (int j = 0; j < 4; j++) {
                int i = j * 256 + tid;
                float v = x[i];
                short h = f2bf(v);
                aa[i] = h;
                aa[E_ + i] = f2bf(v - bf2f(h));
            }
        }
    } else if (task < 3072) {
        int b2 = task - 1024;
        int c0 = (b2 & 31) * 32;
        int r0 = (b2 >> 5) * 32;
        transpose_split(a.fc1w, a.Bt1, E_, r0, c0, 2 * D_, D_, tid, t);
    } else if (task < 4096) {
        int b2 = task - 3072;
        int c0 = (b2 & 31) * 32;
        int r0 = (b2 >> 5) * 32;
        transpose_split(a.fc2w, a.Bt2, E_, r0, c0, 2 * E_, E_, tid, t);
    } else {
        int b2 = task - 4096;
        int c0 = (b2 & 63) * 32;
        int r0 = (b2 >> 6) * 32;
        transpose_split(a.cf, a.cfT, D_, r0, c0, S_, 0, tid, t);
    }
}

// ---------------- 128x128 MFMA GEMM core, nt form, split-K ----------------
struct GP {
    const short* A;
    const short* Bm;
    float* P;
    int M, N, K, Kc, nx, ny;
};

__device__ __forceinline__ void gemm128_core(const GP g, int bid, short* lds) {
    const int tid = threadIdx.x;
    const int per = g.nx * g.ny;
    const int z = bid / per, rem = bid % per;
    const int by = rem / g.nx, bx = rem % g.nx;
    const int bm = by * 128, bn = bx * 128;
    const int kz = z * g.Kc;
    float* C = g.P + (size_t)z * g.M * g.N;
    const short* gA = g.A + (size_t)bm * g.K + kz;
    const short* gB = g.Bm + (size_t)bn * g.K + kz;

    size_t soff[4];
#pragma unroll
    for (int i = 0; i < 4; i++) {
        int ci = tid + i * 256;
        int row = ci >> 3, c = ci & 7;
        soff[i] = (size_t)row * g.K + ((c ^ (row & 7)) << 3);
    }

    auto stage = [&](int buf, int kt) {
        short* base = lds + buf * 16384;
#pragma unroll
        for (int i = 0; i < 4; i++) {
            gload16(gA + soff[i] + kt, base + tid * 8 + i * 2048);
            gload16(gB + soff[i] + kt, base + 8192 + tid * 8 + i * 2048);
        }
    };

    const int lane = tid & 63, wid = tid >> 6;
    const int wr = wid >> 1, wc = wid & 1;
    const int r16 = lane & 15, kg = lane >> 4;
    const int rs7 = (r16 & 7);

    f32x4 acc[4][4] = {};
    const int nt = g.Kc >> 6;

    stage(0, 0);
    for (int t = 0; t < nt; ++t) {
        __syncthreads();
        if (t + 1 < nt) stage((t + 1) & 1, (t + 1) << 6);
        const short* LA = lds + (t & 1) * 16384;
        const short* LB = LA + 8192;
#pragma unroll
        for (int ks = 0; ks < 2; ++ks) {
            const int sw = ((ks * 4 + kg) ^ rs7) << 3;
            bf16x8 a[4], b[4];
#pragma unroll
            for (int m = 0; m < 4; m++)
                a[m] = *(const bf16x8*)(LA + (wr * 64 + m * 16 + r16) * 64 + sw);
#pragma unroll
            for (int n = 0; n < 4; n++)
                b[n] = *(const bf16x8*)(LB + (wc * 64 + n * 16 + r16) * 64 + sw);
#pragma unroll
            for (int m = 0; m < 4; m++)
#pragma unroll
                for (int n = 0; n < 4; n++)
                    acc[m][n] = __builtin_amdgcn_mfma_f32_16x16x32_bf16(a[m], b[n], acc[m][n], 0, 0, 0);
        }
    }
    __syncthreads();

#pragma unroll
    for (int m = 0; m < 4; m++)
#pragma unroll
        for (int n = 0; n < 4; n++) {
            int col = bn + wc * 64 + n * 16 + r16;
#pragma unroll
            for (int r = 0; r < 4; r++) {
                int row = bm + wr * 64 + m * 16 + kg * 4 + r;
                C[(size_t)row * g.N + col] = acc[m][n][r];
            }
        }
}

// ================= single cooperative mega-kernel (256 blocks) =================
__global__ __launch_bounds__(256, 2) void mega(KArgs a) {
    __shared__ __align__(16) char smem[65536];
    const int bid = blockIdx.x;
    const int tid = threadIdx.x;
    cg::grid_group grid = cg::this_grid();

    // ===== P0: prep — 20 tasks/block =====
    {
        float (*t)[33] = (float (*)[33])smem;
        float* red = (float*)(smem + 32 * 33 * sizeof(float) + 16);
        for (int it = 0; it < 20; ++it) {
            prep_task(a, bid + it * 256, tid, t, red);
            __syncthreads();
        }
    }
    __threadfence();
    grid.sync();

    // ===== P1: G1 (KS=4, 128 blk) + G2 (KS=2, 128 blk) =====
    {
        short* lds = (short*)smem;
        if (bid < 128) {
            GP g = {a.A1, a.Bt1, a.P1, S_, E_, 2 * D_, 1024, 8, 4};
            gemm128_core(g, bid, lds);
        } else {
            GP g = {a.A2, a.Bt2, a.P2, B_, E_, 2 * E_, 1024, 8, 8};
            gemm128_core(g, bid - 128, lds);
        }
    }
    __threadfence();
    grid.sync();

    // ===== P2: split-K reduce + BN partial stats =====
    {
        int x = bid & 3, y = bid >> 2;          // y in 0..63
        int c = x * 256 + tid;
        if (y < 32) {                            // branch1: 16 rows, KS=4
            int r0 = y * 16;
            float s = 0.f, ss = 0.f;
            for (int r = r0; r < r0 + 16; r++) {
                float z = 0.f;
#pragma unroll
                for (int k = 0; k < 4; k++) z += a.P1[(size_t)k * S_ * E_ + (size_t)r * E_ + c];
                a.Z1[(size_t)r * E_ + c] = z;
                s += z; ss += z * z;
            }
            a.part1[(size_t)y * 2 * E_ + c] = s;
            a.part1[(size_t)y * 2 * E_ + E_ + c] = ss;
        } else {                                 // branch2: 32 rows, KS=2
            int y2 = y - 32;
            int r0 = y2 * 32;
            float s = 0.f, ss = 0.f;
            for (int r = r0; r < r0 + 32; r++) {
                float z = 0.f;
#pragma unroll
                for (int k = 0; k < 2; k++) z += a.P2[(size_t)k * B_ * E_ + (size_t)r * E_ + c];
                a.Z2[(size_t)r * E_ + c] = z;
                s += z; ss += z * z;
            }
            a.part2[(size_t)y2 * 2 * E_ + c] = s;
            a.part2[(size_t)y2 * 2 * E_ + E_ + c] = ss;
        }
    }
    __threadfence();
    grid.sync();

    // ===== P3: BN finalize + tanh (+fc3) -> concat-K bf16 pairs =====
    {
        int x = bid & 3, y = bid >> 2;           // y in 0..63
        bool br1 = y < 32;
        int c = x * 256 + tid;
        const float* part = br1 ? a.part1 : a.part2;
        float s = 0.f, ss = 0.f;
#pragma unroll
        for (int k = 0; k < 32; k++) {
            s += part[(size_t)k * 2 * E_ + c];
            ss += part[(size_t)k * 2 * E_ + E_ + c];
        }
        float invR = br1 ? (1.0f / 512.0f) : (1.0f / 1024.0f);
        float mu = s * invR;
        float var = ss * invR - mu * mu;
        float rstd = rsqrtf(var + 1e-5f);
        float Aa = (br1 ? a.bn1g[c] : a.bn2g[c]) * rstd;
        float Bb = (br1 ? a.bn1b[c] : a.bn2b[c]) - Aa * mu;
        float sc = br1 ? 1.0f : a.fc3w[c];
        const float* Z = br1 ? a.Z1 : a.Z2;
        short* W = br1 ? a.Ws : a.Wv3;
        int nr = br1 ? 16 : 32;
        int r0 = (br1 ? y : (y - 32)) * nr;
        for (int r = r0; r < r0 + nr; r++) {
            float w = tanhf(fmaf(Z[(size_t)r * E_ + c], Aa, Bb)) * sc;
            short h = f2bf(w);
            size_t o = (size_t)r * (2 * E_) + c;
            W[o] = h;
            W[o + E_] = f2bf(w - bf2f(h));
        }
    }
    __threadfence();
    grid.sync();

    // ===== P4: G3 a_s partials = Wv3 @ Ws^T (KS=8, 256 blk) =====
    {
        short* lds = (short*)smem;
        GP g = {a.Wv3, a.Ws, a.P3, B_, S_, 2 * E_, 256, 4, 8};
        gemm128_core(g, bid, lds);
    }
    __threadfence();
    grid.sync();

    // ===== P5: softmax (4 rows/block), fp32 out + invn-scaled bf16 =====
    {
        float* red = (float*)smem;
        for (int rr = 0; rr < 4; ++rr) {
            int row = bid * 4 + rr;
            float v0 = 0.f, v1 = 0.f;
#pragma unroll
            for (int k = 0; k < 8; k++) {
                v0 += a.P3[(size_t)k * B_ * S_ + (size_t)row * S_ + tid];
                v1 += a.P3[(size_t)k * B_ * S_ + (size_t)row * S_ + tid + 256];
            }
            v0 *= SMOOTH;
            v1 *= SMOOTH;
            float m = waveReduceMax(fmaxf(v0, v1));
            if ((tid & 63) == 0) red[tid >> 6] = m;
            __syncthreads();
            m = fmaxf(fmaxf(red[0], red[1]), fmaxf(red[2], red[3]));
            float e0 = __expf(v0 - m), e1 = __expf(v1 - m);
            float s = waveReduceSum(e0 + e1);
            __syncthreads();
            if ((tid & 63) == 0) red[tid >> 6] = s;
            __syncthreads();
            s = red[0] + red[1] + red[2] + red[3];
            float inv = 1.0f / s;
            float w0 = e0 * inv, w1 = e1 * inv;
            a.weights_v[(size_t)row * S_ + tid] = w0;
            a.weights_v[(size_t)row * S_ + tid + 256] = w1;
            a.A4[(size_t)row * S_ + tid] = f2bf(w0 * a.invn[tid]);
            a.A4[(size_t)row * S_ + tid + 256] = f2bf(w1 * a.invn[tid + 256]);
            __syncthreads();
        }
    }
    __threadfence();
    grid.sync();

    // ===== P6: G4 emb_pre partials = A4 @ cfT^T (KS=2, 256 blk) =====
    {
        short* lds = (short*)smem;
        GP g = {a.A4, a.cfT, a.P4, B_, D_, S_, 256, 16, 8};
        gemm128_core(g, bid, lds);
    }
    __threadfence();
    grid.sync();

    // ===== P7: reduce 2 slices + row l2norm (4 rows/block) =====
    {
        float* red = (float*)smem;
        for (int rr = 0; rr < 4; ++rr) {
            int row = bid * 4 + rr;
            float v[8];
            float ss = 0.f;
#pragma unroll
            for (int j = 0; j < 8; j++) {
                size_t idx = (size_t)row * D_ + j * 256 + tid;
                v[j] = a.P4[idx] + a.P4[(size_t)B_ * D_ + idx];
                ss += v[j] * v[j];
            }
            ss = waveReduceSum(ss);
            if ((tid & 63) == 0) red[tid >> 6] = ss;
            __syncthreads();
            ss = red[0] + red[1] + red[2] + red[3];
            float sc = 1.0f / (sqrtf(ss) + 1e-8f);
#pragma unroll
            for (int j = 0; j < 8; j++)
                a.emb_concept[(size_t)row * D_ + j * 256 + tid] = v[j] * sc;
            __syncthreads();
        }
    }
}

// ================= fallback kernels (proven R6 pipeline) =================
__global__ __launch_bounds__(256) void prep_k(KArgs a) {
    __shared__ float t[32][33];
    __shared__ float red[4];
    prep_task(a, blockIdx.x, threadIdx.x, t, red);
}

__global__ __launch_bounds__(256) void gemm_dual(GP g0, GP g1, int n0) {
    __shared__ short lds[32768];
    int bid = blockIdx.x;
    if (bid < n0) gemm128_core(g0, bid, lds);
    else gemm128_core(g1, bid - n0, lds);
}

__global__ __launch_bounds__(256) void gemm_one(GP g) {
    __shared__ short lds[32768];
    gemm128_core(g, blockIdx.x, lds);
}

__global__ __launch_bounds__(256) void bn_stats12(KArgs a) {
    int c = blockIdx.x * 256 + threadIdx.x;
    if (blockIdx.y < 32) {
        int r0 = blockIdx.y * 16;
        float s = 0.f, ss = 0.f;
        for (int r = r0; r < r0 + 16; r++) {
            float z = 0.f;
#pragma unroll
            for (int k = 0; k < 4; k++) z += a.P1[(size_t)k * S_ * E_ + (size_t)r * E_ + c];
            a.Z1[(size_t)r * E_ + c] = z;
            s += z; ss += z * z;
        }
        a.part1[(size_t)blockIdx.y * 2 * E_ + c] = s;
        a.part1[(size_t)blockIdx.y * 2 * E_ + E_ + c] = ss;
    } else {
        int y2 = blockIdx.y - 32;
        int r0 = y2 * 32;
        float s = 0.f, ss = 0.f;
        for (int r = r0; r < r0 + 32; r++) {
            float z = 0.f;
#pragma unroll
            for (int k = 0; k < 2; k++) z += a.P2[(size_t)k * B_ * E_ + (size_t)r * E_ + c];
            a.Z2[(size_t)r * E_ + c] = z;
            s += z; ss += z * z;
        }
        a.part2[(size_t)y2 * 2 * E_ + c] = s;
        a.part2[(size_t)y2 * 2 * E_ + E_ + c] = ss;
    }
}

__global__ __launch_bounds__(256) void bn_apply12(KArgs a) {
    int c = blockIdx.x * 256 + threadIdx.x;
    bool br1 = blockIdx.y < 32;
    const float* part = br1 ? a.part1 : a.part2;
    float s = 0.f, ss = 0.f;
#pragma unroll
    for (int k = 0; k < 32; k++) {
        s += part[(size_t)k * 2 * E_ + c];
        ss += part[(size_t)k * 2 * E_ + E_ + c];
    }
    float invR = br1 ? (1.0f / 512.0f) : (1.0f / 1024.0f);
    float mu = s * invR;
    float var = ss * invR - mu * mu;
    float rstd = rsqrtf(var + 1e-5f);
    float Aa = (br1 ? a.bn1g[c] : a.bn2g[c]) * rstd;
    float Bb = (br1 ? a.bn1b[c] : a.bn2b[c]) - Aa * mu;
    float sc = br1 ? 1.0f : a.fc3w[c];
    const float* Z = br1 ? a.Z1 : a.Z2;
    short* W = br1 ? a.Ws : a.Wv3;
    int nr = br1 ? 16 : 32;
    int r0 = (br1 ? blockIdx.y : (blockIdx.y - 32)) * nr;
    for (int r = r0; r < r0 + nr; r++) {
        float w = tanhf(fmaf(Z[(size_t)r * E_ + c], Aa, Bb)) * sc;
        short h = f2bf(w);
        size_t o = (size_t)r * (2 * E_) + c;
        W[o] = h;
        W[o + E_] = f2bf(w - bf2f(h));
    }
}

__global__ __launch_bounds__(256) void softmax_k(KArgs a, int KS) {
    __shared__ float red[4];
    int row = blockIdx.x;
    int tid = threadIdx.x;
    float v0 = 0.f, v1 = 0.f;
    for (int k = 0; k < KS; k++) {
        v0 += a.P3[(size_t)k * B_ * S_ + (size_t)row * S_ + tid];
        v1 += a.P3[(size_t)k * B_ * S_ + (size_t)row * S_ + tid + 256];
    }
    v0 *= SMOOTH;
    v1 *= SMOOTH;
    float m = waveReduceMax(fmaxf(v0, v1));
    if ((tid & 63) == 0) red[tid >> 6] = m;
    __syncthreads();
    m = fmaxf(fmaxf(red[0], red[1]), fmaxf(red[2], red[3]));
    float e0 = __expf(v0 - m), e1 = __expf(v1 - m);
    float s = waveReduceSum(e0 + e1);
    __syncthreads();
    if ((tid & 63) == 0) red[tid >> 6] = s;
    __syncthreads();
    s = red[0] + red[1] + red[2] + red[3];
    float inv = 1.0f / s;
    float w0 = e0 * inv, w1 = e1 * inv;
    a.weights_v[(size_t)row * S_ + tid] = w0;
    a.weights_v[(size_t)row * S_ + tid + 256] = w1;
    a.A4[(size_t)row * S_ + tid] = f2bf(w0 * a.invn[tid]);
    a.A4[(size_t)row * S_ + tid + 256] = f2bf(w1 * a.invn[tid + 256]);
}

__global__ __launch_bounds__(256) void rownorm_k(KArgs a, int nslice) {
    __shared__ float red[4];
    int row = blockIdx.x;
    int tid = threadIdx.x;
    float v[8];
    float ss = 0.f;
#pragma unroll
    for (int j = 0; j < 8; j++) {
        size_t idx = (size_t)row * D_ + j * 256 + tid;
        v[j] = a.P4[idx];
        if (nslice == 2) v[j] += a.P4[(size_t)B_ * D_ + idx];
        ss += v[j] * v[j];
    }
    ss = waveReduceSum(ss);
    if ((tid & 63) == 0) red[tid >> 6] = ss;
    __syncthreads();
    ss = red[0] + red[1] + red[2] + red[3];
    float sc = 1.0f / (sqrtf(ss) + 1e-8f);
#pragma unroll
    for (int j = 0; j < 8; j++)
        a.emb_concept[(size_t)row * D_ + j * 256 + tid] = v[j] * sc;
}

extern "C" void kernel_launch(void* const* d_in, const int* in_sizes, int n_in,
                              void* d_out, int out_size, void* d_ws, size_t ws_size,
                              hipStream_t stream) {
    float* out = (float*)d_out;
    const size_t MB = 1024 * 1024;
    char* w = (char*)d_ws;

    KArgs a;
    a.cf   = (const float*)d_in[1];
    a.emb  = (const float*)d_in[0];
    a.fc1w = (const float*)d_in[3];
    a.fc2w = (const float*)d_in[7];
    a.bn1g = (const float*)d_in[5];
    a.bn1b = (const float*)d_in[6];
    a.bn2g = (const float*)d_in[9];
    a.bn2b = (const float*)d_in[10];
    a.fc3w = (const float*)d_in[11];
    a.Bt1  = (short*)(w + 0 * MB);            // 8MB
    a.A1   = (short*)(w + 8 * MB);            // 4MB
    a.A2   = (short*)(w + 12 * MB);           // 4MB
    a.Bt2  = (short*)(w + 16 * MB);           // 4MB
    a.cfT  = (short*)(w + 20 * MB);           // 2MB
    a.Z1   = (float*)(w + 22 * MB);           // 2MB
    a.Z2   = (float*)(w + 24 * MB);           // 4MB
    a.Ws   = (short*)(w + 28 * MB);           // 2MB
    a.Wv3  = (short*)(w + 30 * MB);           // 4MB
    a.A4   = (short*)(w + 34 * MB);           // 1MB
    a.part1 = (float*)(w + 35 * MB);          // 32*2*E*4 = 256KB
    a.part2 = (float*)(w + 35 * MB + 512 * 1024);
    a.invn  = (float*)(w + 36 * MB);
    a.P1   = (float*)(w + 40 * MB);           // KS=4 x 2MB = 8MB
    a.P2   = (float*)(w + 56 * MB);           // KS=2 x 4MB = 8MB
    a.P3   = (float*)(w + 40 * MB);           // KS=8 x 2MB = 16MB (aliases P1, dead)
    a.P4   = (float*)(w + 56 * MB);           // KS=2 x 8MB = 16MB (aliases P2, dead)
    a.emb_concept = out;
    a.weights_v   = out + (size_t)B_ * D_;

    void* params[] = { (void*)&a };
    hipError_t err = hipLaunchCooperativeKernel((void*)mega, dim3(256), dim3(256),
                                                params, 0, stream);
    if (err == hipSuccess) return;

    // ---------- fallback: proven 8-launch pipeline (R6 structure) ----------
    prep_k<<<5120, 256, 0, stream>>>(a);

    GP g1 = {a.A1, a.Bt1, a.P1, S_, E_, 2 * D_, 1024, 8, 4};
    GP g2 = {a.A2, a.Bt2, a.P2, B_, E_, 2 * E_, 1024, 8, 8};
    gemm_dual<<<256, 256, 0, stream>>>(g1, g2, 128);

    bn_stats12<<<dim3(4, 64), 256, 0, stream>>>(a);
    bn_apply12<<<dim3(4, 64), 256, 0, stream>>>(a);

    GP g3 = {a.Wv3, a.Ws, a.P3, B_, S_, 2 * E_, 512, 4, 8};   // KS=4
    gemm_one<<<128, 256, 0, stream>>>(g3);

    softmax_k<<<B_, 256, 0, stream>>>(a, 4);

    GP g4 = {a.A4, a.cfT, a.P4, B_, D_, S_, 512, 16, 8};      // KS=1
    gemm_one<<<128, 256, 0, stream>>>(g4);

    rownorm_k<<<B_, 256, 0, stream>>>(a, 1);
}

// Round 9
// 74.801 us; speedup vs baseline: 6.5311x; 6.5311x over previous
//
#include <hip/hip_runtime.h>
#include <hip/hip_bf16.h>
#include <math.h>

#define B_ 1024
#define S_ 512
#define E_ 1024
#define D_ 2048
#define SMOOTH 10.0f

typedef __attribute__((ext_vector_type(8))) short bf16x8;
typedef __attribute__((ext_vector_type(4))) float f32x4;

__device__ __forceinline__ short f2bf(float f) {
    __hip_bfloat16 h = __float2bfloat16(f);
    short s; __builtin_memcpy(&s, &h, 2); return s;
}

__device__ __forceinline__ void gload16(const short* g, short* l) {
    __builtin_amdgcn_global_load_lds(
        (const __attribute__((address_space(1))) void*)(g),
        (__attribute__((address_space(3))) void*)(l), 16, 0, 0);
}

__inline__ __device__ float waveReduceMax(float v) {
#pragma unroll
    for (int o = 32; o; o >>= 1) v = fmaxf(v, __shfl_xor(v, o));
    return v;
}
__inline__ __device__ float waveReduceSum(float v) {
#pragma unroll
    for (int o = 32; o; o >>= 1) v += __shfl_xor(v, o);
    return v;
}

// ---------------- args ----------------
struct KArgs {
    const float *cf, *emb, *fc1w, *fc2w, *bn1g, *bn1b, *bn2g, *bn2b, *fc3w;
    short *A1, *A2, *Bt1, *Bt2, *cfT, *Ws, *Wv3, *A4;
    float *invn, *Z1, *Z2, *part1, *part2, *P1, *P2, *P3, *emb_pre;
    float *weights_v, *emb_concept;
};

// ---------------- transpose helper (32x32 tile via LDS), bf16 out ----------------
__device__ __forceinline__ void transpose_bf(const float* __restrict__ in,
                                             short* __restrict__ out,
                                             int C, int r0, int c0, int ldo,
                                             int tid, float (*t)[33]) {
    int cx = tid & 31, ry0 = tid >> 5;
#pragma unroll
    for (int i = 0; i < 4; i++) {
        int ry = ry0 + i * 8;
        t[ry][cx] = in[(size_t)(r0 + ry) * C + c0 + cx];
    }
    __syncthreads();
    int rx = tid & 31, cy0 = tid >> 5;
#pragma unroll
    for (int i = 0; i < 4; i++) {
        int cy = cy0 + i * 8;
        out[(size_t)(c0 + cy) * ldo + r0 + rx] = f2bf(t[rx][cy]);
    }
}

// ---------------- prep: conversions / transposes / invnorm, task-segmented ----------------
// [0,512):      cf row -> A1 bf16 (512x2048) + invn
// [512,1024):   emb (2 rows/blk) -> A2 bf16 (1024x1024)
// [1024,3072):  fc1_w (2048x1024) -> Bt1 (1024x2048) bf16-T
// [3072,4096):  fc2_w (1024x1024) -> Bt2 (1024x1024) bf16-T
// [4096,5120):  cf (512x2048) -> cfT (2048x512) bf16-T
__global__ __launch_bounds__(256) void prep_k(KArgs a) {
    __shared__ float t[32][33];
    __shared__ float red[4];
    const int task = blockIdx.x;
    const int tid = threadIdx.x;
    if (task < 512) {
        int row = task;
        const float* x = a.cf + (size_t)row * D_;
        short* aa = a.A1 + (size_t)row * D_;
        float ss = 0.f;
#pragma unroll
        for (int j = 0; j < 8; j++) {
            int i = j * 256 + tid;
            float v = x[i];
            aa[i] = f2bf(v);
            ss += v * v;
        }
        ss = waveReduceSum(ss);
        if ((tid & 63) == 0) red[tid >> 6] = ss;
        __syncthreads();
        if (tid == 0) {
            float s = red[0] + red[1] + red[2] + red[3];
            a.invn[row] = 1.0f / (sqrtf(s) + 1e-8f);
        }
    } else if (task < 1024) {
        int r0 = (task - 512) * 2;
#pragma unroll
        for (int rr = 0; rr < 2; rr++) {
            int row = r0 + rr;
            const float* x = a.emb + (size_t)row * E_;
            short* aa = a.A2 + (size_t)row * E_;
#pragma unroll
            for (int j = 0; j < 4; j++) {
                int i = j * 256 + tid;
                aa[i] = f2bf(x[i]);
            }
        }
    } else if (task < 3072) {
        int b2 = task - 1024;
        int c0 = (b2 & 31) * 32;   // over E
        int r0 = (b2 >> 5) * 32;   // over D
        transpose_bf(a.fc1w, a.Bt1, E_, r0, c0, D_, tid, t);
    } else if (task < 4096) {
        int b2 = task - 3072;
        int c0 = (b2 & 31) * 32;
        int r0 = (b2 >> 5) * 32;
        transpose_bf(a.fc2w, a.Bt2, E_, r0, c0, E_, tid, t);
    } else {
        int b2 = task - 4096;
        int c0 = (b2 & 63) * 32;   // over D
        int r0 = (b2 >> 6) * 32;   // over S
        transpose_bf(a.cf, a.cfT, D_, r0, c0, S_, tid, t);
    }
}

// ---------------- 128x128 MFMA GEMM core, nt form, split-K ----------------
struct GP {
    const short* A;
    const short* Bm;
    float* P;
    int M, N, K, Kc, nx, ny;
};

__device__ __forceinline__ void gemm128_core(const GP g, int bid, short* lds) {
    const int tid = threadIdx.x;
    const int per = g.nx * g.ny;
    const int z = bid / per, rem = bid % per;
    const int by = rem / g.nx, bx = rem % g.nx;
    const int bm = by * 128, bn = bx * 128;
    const int kz = z * g.Kc;
    float* C = g.P + (size_t)z * g.M * g.N;
    const short* gA = g.A + (size_t)bm * g.K + kz;
    const short* gB = g.Bm + (size_t)bn * g.K + kz;

    size_t soff[4];
#pragma unroll
    for (int i = 0; i < 4; i++) {
        int ci = tid + i * 256;
        int row = ci >> 3, c = ci & 7;
        soff[i] = (size_t)row * g.K + ((c ^ (row & 7)) << 3);
    }

    auto stage = [&](int buf, int kt) {
        short* base = lds + buf * 16384;
#pragma unroll
        for (int i = 0; i < 4; i++) {
            gload16(gA + soff[i] + kt, base + tid * 8 + i * 2048);
            gload16(gB + soff[i] + kt, base + 8192 + tid * 8 + i * 2048);
        }
    };

    const int lane = tid & 63, wid = tid >> 6;
    const int wr = wid >> 1, wc = wid & 1;
    const int r16 = lane & 15, kg = lane >> 4;
    const int rs7 = (r16 & 7);

    f32x4 acc[4][4] = {};
    const int nt = g.Kc >> 6;

    stage(0, 0);
    for (int t = 0; t < nt; ++t) {
        __syncthreads();
        if (t + 1 < nt) stage((t + 1) & 1, (t + 1) << 6);
        const short* LA = lds + (t & 1) * 16384;
        const short* LB = LA + 8192;
#pragma unroll
        for (int ks = 0; ks < 2; ++ks) {
            const int sw = ((ks * 4 + kg) ^ rs7) << 3;
            bf16x8 a[4], b[4];
#pragma unroll
            for (int m = 0; m < 4; m++)
                a[m] = *(const bf16x8*)(LA + (wr * 64 + m * 16 + r16) * 64 + sw);
#pragma unroll
            for (int n = 0; n < 4; n++)
                b[n] = *(const bf16x8*)(LB + (wc * 64 + n * 16 + r16) * 64 + sw);
#pragma unroll
            for (int m = 0; m < 4; m++)
#pragma unroll
                for (int n = 0; n < 4; n++)
                    acc[m][n] = __builtin_amdgcn_mfma_f32_16x16x32_bf16(a[m], b[n], acc[m][n], 0, 0, 0);
        }
    }

#pragma unroll
    for (int m = 0; m < 4; m++)
#pragma unroll
        for (int n = 0; n < 4; n++) {
            int col = bn + wc * 64 + n * 16 + r16;
#pragma unroll
            for (int r = 0; r < 4; r++) {
                int row = bm + wr * 64 + m * 16 + kg * 4 + r;
                C[(size_t)row * g.N + col] = acc[m][n][r];
            }
        }
}

__global__ __launch_bounds__(256) void gemm_dual(GP g0, GP g1, int n0) {
    __shared__ short lds[32768];
    int bid = blockIdx.x;
    if (bid < n0) gemm128_core(g0, bid, lds);
    else gemm128_core(g1, bid - n0, lds);
}

__global__ __launch_bounds__(256) void gemm_one(GP g) {
    __shared__ short lds[32768];
    gemm128_core(g, blockIdx.x, lds);
}

// ---------------- split-K reduce + BN partial stats (both branches) ----------------
// grid (4, 64): y<32 -> branch1 (S=512, KS=4, 16 rows); y>=32 -> branch2 (B=1024, KS=2, 32 rows)
__global__ __launch_bounds__(256) void bn_stats12(KArgs a) {
    int c = blockIdx.x * 256 + threadIdx.x;
    if (blockIdx.y < 32) {
        int r0 = blockIdx.y * 16;
        float s = 0.f, ss = 0.f;
        for (int r = r0; r < r0 + 16; r++) {
            float z = 0.f;
#pragma unroll
            for (int k = 0; k < 4; k++) z += a.P1[(size_t)k * S_ * E_ + (size_t)r * E_ + c];
            a.Z1[(size_t)r * E_ + c] = z;
            s += z; ss += z * z;
        }
        a.part1[(size_t)blockIdx.y * 2 * E_ + c] = s;
        a.part1[(size_t)blockIdx.y * 2 * E_ + E_ + c] = ss;
    } else {
        int y2 = blockIdx.y - 32;
        int r0 = y2 * 32;
        float s = 0.f, ss = 0.f;
        for (int r = r0; r < r0 + 32; r++) {
            float z = 0.f;
#pragma unroll
            for (int k = 0; k < 2; k++) z += a.P2[(size_t)k * B_ * E_ + (size_t)r * E_ + c];
            a.Z2[(size_t)r * E_ + c] = z;
            s += z; ss += z * z;
        }
        a.part2[(size_t)y2 * 2 * E_ + c] = s;
        a.part2[(size_t)y2 * 2 * E_ + E_ + c] = ss;
    }
}

// ---------------- BN finalize + tanh (+fc3 scale) -> bf16 ----------------
__global__ __launch_bounds__(256) void bn_apply12(KArgs a) {
    int c = blockIdx.x * 256 + threadIdx.x;
    bool br1 = blockIdx.y < 32;
    const float* part = br1 ? a.part1 : a.part2;
    float s = 0.f, ss = 0.f;
#pragma unroll
    for (int k = 0; k < 32; k++) {
        s += part[(size_t)k * 2 * E_ + c];
        ss += part[(size_t)k * 2 * E_ + E_ + c];
    }
    float invR = br1 ? (1.0f / 512.0f) : (1.0f / 1024.0f);
    float mu = s * invR;
    float var = ss * invR - mu * mu;
    float rstd = rsqrtf(var + 1e-5f);
    float Aa = (br1 ? a.bn1g[c] : a.bn2g[c]) * rstd;
    float Bb = (br1 ? a.bn1b[c] : a.bn2b[c]) - Aa * mu;
    float sc = br1 ? 1.0f : a.fc3w[c];
    const float* Z = br1 ? a.Z1 : a.Z2;
    short* W = br1 ? a.Ws : a.Wv3;
    int nr = br1 ? 16 : 32;
    int r0 = (br1 ? blockIdx.y : (blockIdx.y - 32)) * nr;
    for (int r = r0; r < r0 + nr; r++) {
        float w = tanhf(fmaf(Z[(size_t)r * E_ + c], Aa, Bb)) * sc;
        W[(size_t)r * E_ + c] = f2bf(w);
    }
}

// ---------------- split-K reduce (KS=4) + row softmax, fp32 out + invn-scaled bf16 ----------------
__global__ __launch_bounds__(256) void softmax_k(KArgs a) {
    __shared__ float red[4];
    int row = blockIdx.x;
    int tid = threadIdx.x;
    float v0 = 0.f, v1 = 0.f;
#pragma unroll
    for (int k = 0; k < 4; k++) {
        v0 += a.P3[(size_t)k * B_ * S_ + (size_t)row * S_ + tid];
        v1 += a.P3[(size_t)k * B_ * S_ + (size_t)row * S_ + tid + 256];
    }
    v0 *= SMOOTH;
    v1 *= SMOOTH;
    float m = waveReduceMax(fmaxf(v0, v1));
    if ((tid & 63) == 0) red[tid >> 6] = m;
    __syncthreads();
    m = fmaxf(fmaxf(red[0], red[1]), fmaxf(red[2], red[3]));
    float e0 = __expf(v0 - m), e1 = __expf(v1 - m);
    float s = waveReduceSum(e0 + e1);
    __syncthreads();
    if ((tid & 63) == 0) red[tid >> 6] = s;
    __syncthreads();
    s = red[0] + red[1] + red[2] + red[3];
    float inv = 1.0f / s;
    float w0 = e0 * inv, w1 = e1 * inv;
    a.weights_v[(size_t)row * S_ + tid] = w0;
    a.weights_v[(size_t)row * S_ + tid + 256] = w1;
    a.A4[(size_t)row * S_ + tid] = f2bf(w0 * a.invn[tid]);
    a.A4[(size_t)row * S_ + tid + 256] = f2bf(w1 * a.invn[tid + 256]);
}

// ---------------- row l2norm -> output ----------------
__global__ __launch_bounds__(256) void rownorm_k(KArgs a) {
    __shared__ float red[4];
    int row = blockIdx.x;
    int tid = threadIdx.x;
    float v[8];
    float ss = 0.f;
#pragma unroll
    for (int j = 0; j < 8; j++) {
        v[j] = a.emb_pre[(size_t)row * D_ + j * 256 + tid];
        ss += v[j] * v[j];
    }
    ss = waveReduceSum(ss);
    if ((tid & 63) == 0) red[tid >> 6] = ss;
    __syncthreads();
    ss = red[0] + red[1] + red[2] + red[3];
    float sc = 1.0f / (sqrtf(ss) + 1e-8f);
#pragma unroll
    for (int j = 0; j < 8; j++)
        a.emb_concept[(size_t)row * D_ + j * 256 + tid] = v[j] * sc;
}

extern "C" void kernel_launch(void* const* d_in, const int* in_sizes, int n_in,
                              void* d_out, int out_size, void* d_ws, size_t ws_size,
                              hipStream_t stream) {
    float* out = (float*)d_out;
    const size_t MB = 1024 * 1024;
    char* w = (char*)d_ws;

    KArgs a;
    a.cf   = (const float*)d_in[1];
    a.emb  = (const float*)d_in[0];
    a.fc1w = (const float*)d_in[3];
    a.fc2w = (const float*)d_in[7];
    a.bn1g = (const float*)d_in[5];
    a.bn1b = (const float*)d_in[6];
    a.bn2g = (const float*)d_in[9];
    a.bn2b = (const float*)d_in[10];
    a.fc3w = (const float*)d_in[11];
    a.Bt1  = (short*)(w + 0 * MB);            // 1024x2048 bf16 = 4MB
    a.Bt2  = (short*)(w + 4 * MB);            // 1024x1024 = 2MB
    a.A1   = (short*)(w + 6 * MB);            // 512x2048 = 2MB
    a.A2   = (short*)(w + 8 * MB);            // 1024x1024 = 2MB
    a.cfT  = (short*)(w + 10 * MB);           // 2048x512 = 2MB
    a.Z1   = (float*)(w + 12 * MB);           // 2MB
    a.Z2   = (float*)(w + 14 * MB);           // 4MB
    a.Ws   = (short*)(w + 18 * MB);           // 512x1024 = 1MB
    a.Wv3  = (short*)(w + 19 * MB);           // 1024x1024 = 2MB
    a.A4   = (short*)(w + 21 * MB);           // 1024x512 = 1MB
    a.part1 = (float*)(w + 22 * MB);          // 32*2*E*4 = 256KB
    a.part2 = (float*)(w + 22 * MB + 512 * 1024);
    a.invn  = (float*)(w + 23 * MB);
    a.P1   = (float*)(w + 24 * MB);           // KS=4 x 2MB = 8MB
    a.P2   = (float*)(w + 32 * MB);           // KS=2 x 4MB = 8MB
    a.P3   = (float*)(w + 24 * MB);           // KS=4 x 2MB = 8MB (aliases P1, dead by then)
    a.emb_pre = (float*)(w + 32 * MB);        // 8MB (aliases P2, dead by then)
    a.emb_concept = out;
    a.weights_v   = out + (size_t)B_ * D_;

    // 1. conversions/transposes/invnorm
    prep_k<<<5120, 256, 0, stream>>>(a);

    // 2. G1 (512x1024x2048, KS=4) + G2 (1024x1024x1024, KS=2) — 256 blocks
    GP g1 = {a.A1, a.Bt1, a.P1, S_, E_, D_, 512, 8, 4};
    GP g2 = {a.A2, a.Bt2, a.P2, B_, E_, E_, 512, 8, 8};
    gemm_dual<<<256, 256, 0, stream>>>(g1, g2, 128);

    // 3+4. BN stats + apply (both branches)
    bn_stats12<<<dim3(4, 64), 256, 0, stream>>>(a);
    bn_apply12<<<dim3(4, 64), 256, 0, stream>>>(a);

    // 5. G3: a_s partials = Wv3 @ Ws^T (1024x512x1024, KS=4) — 128 blocks
    GP g3 = {a.Wv3, a.Ws, a.P3, B_, S_, E_, 256, 4, 8};
    gemm_one<<<128, 256, 0, stream>>>(g3);

    // 6. softmax + A4 = bf16(w * invn)
    softmax_k<<<B_, 256, 0, stream>>>(a);

    // 7. G4: emb_pre = A4 @ cfT^T (1024x2048x512, KS=1) — 128 blocks
    GP g4 = {a.A4, a.cfT, a.emb_pre, B_, D_, S_, 512, 16, 8};
    gemm_one<<<128, 256, 0, stream>>>(g4);

    // 8. emb_concept = l2norm(emb_pre)
    rownorm_k<<<B_, 256, 0, stream>>>(a);
}